// Round 6
// baseline (269.075 us; speedup 1.0000x reference)
//
#include <hip/hip_runtime.h>
#include <hip/hip_bf16.h>

// Problem constants
#define B_  32
#define T_  512
#define D_  512
#define HD_ 64
#define HN_ 16
#define O_  512
#define M_  (B_ * T_)      // 16384 rows
#define NQ_ (HN_ * HD_)    // 1024 qkv cols

typedef __bf16 bf16;
typedef __attribute__((ext_vector_type(8))) __bf16 bf16x8;
typedef __attribute__((ext_vector_type(4))) __bf16 bf16x4;
typedef __attribute__((ext_vector_type(4))) float f32x4;

static __device__ __forceinline__ f32x4 mfma16(bf16x8 a, bf16x8 b, f32x4 c) {
    return __builtin_amdgcn_mfma_f32_16x16x32_bf16(a, b, c, 0, 0, 0);
}

// Direct global->LDS 16B copy.
static __device__ __forceinline__ void load_lds_16B(const bf16* g, bf16* l) {
    __builtin_amdgcn_global_load_lds(
        (const __attribute__((address_space(1))) unsigned int*)(unsigned long long)g,
        (__attribute__((address_space(3))) unsigned int*)(unsigned long long)l,
        16, 0, 0);
}

static __device__ __forceinline__ float fast_tanh(float x) {
    return 1.f - 2.f / (__expf(2.f * x) + 1.f);
}

// T1 chunked XCD swizzle: requires (gridDim.x*gridDim.y) % 8 == 0.
static __device__ __forceinline__ int2 swz_block() {
    const int nx = gridDim.x;
    const int nwg = nx * gridDim.y;
    int l = blockIdx.y * nx + blockIdx.x;
    l = (l & 7) * (nwg >> 3) + (l >> 3);
    return make_int2(l % nx, l / nx);
}

// ---------------------------------------------------------------------------
// Weight prep (LDS-tiled, coalesced both sides).
// ---------------------------------------------------------------------------
__global__ __launch_bounds__(256) void prep_headw_kernel(
    const float* __restrict__ Wq, const float* __restrict__ Wk,
    const float* __restrict__ Wv, bf16* __restrict__ wall)
{
    __shared__ bf16 tl[64][72];
    int id = blockIdx.x;                 // [src(3)][h(16)][kt(8)]
    const int kt = id & 7; id >>= 3;
    const int h = id & 15; id >>= 4;
    const float* src = (id == 0) ? Wq : (id == 1) ? Wk : Wv;
    bf16* dst = wall + (size_t)id * (1024 * 512);
    const int tid = threadIdx.x;
    const int k0 = kt * 64;
#pragma unroll
    for (int i = 0; i < 4; i++) {
        const int e = i * 256 + tid;
        const int kk = e >> 4, f4 = (e & 15) * 4;
        const f32x4 v = *(const f32x4*)(src + ((size_t)h * 512 + k0 + kk) * 64 + f4);
#pragma unroll
        for (int j = 0; j < 4; j++) tl[f4 + j][kk] = (bf16)v[j];
    }
    __syncthreads();
#pragma unroll
    for (int i = 0; i < 2; i++) {
        const int e = i * 256 + tid;
        const int f = e >> 3, kc = (e & 7) * 8;
        *(bf16x8*)(dst + ((size_t)h * 64 + f) * 512 + k0 + kc) = *(const bf16x8*)&tl[f][kc];
    }
}

__global__ __launch_bounds__(256) void prep_plain_kernel(
    const float* __restrict__ Wr, const float* __restrict__ Wo,
    const float* __restrict__ Wfc,
    bf16* __restrict__ wrt, bf16* __restrict__ wot, bf16* __restrict__ wfct)
{
    __shared__ bf16 tl[64][72];
    int id = blockIdx.x;                 // Wr:0..63  Wo:64..191  Wfc:192..255
    const float* src; bf16* dst; int K;
    if (id < 64)       { src = Wr;  dst = wrt;  K = 512;  }
    else if (id < 192) { src = Wo;  dst = wot;  K = 1024; id -= 64; }
    else               { src = Wfc; dst = wfct; K = 512;  id -= 192; }
    const int kt = id >> 3, nt = id & 7;
    const int k0 = kt * 64, n0 = nt * 64;
    const int tid = threadIdx.x;
#pragma unroll
    for (int i = 0; i < 4; i++) {
        const int e = i * 256 + tid;
        const int kk = e >> 4, n4 = (e & 15) * 4;
        const f32x4 v = *(const f32x4*)(src + (size_t)(k0 + kk) * 512 + n0 + n4);
#pragma unroll
        for (int j = 0; j < 4; j++) tl[n4 + j][kk] = (bf16)v[j];
    }
    __syncthreads();
#pragma unroll
    for (int i = 0; i < 2; i++) {
        const int e = i * 256 + tid;
        const int nn = e >> 3, kc = (e & 7) * 8;
        *(bf16x8*)(dst + (size_t)(n0 + nn) * K + k0 + kc) = *(const bf16x8*)&tl[nn][kc];
    }
}

__global__ __launch_bounds__(256) void conv_input_kernel(
    const float* __restrict__ in, bf16* __restrict__ out)
{
    const size_t i = ((size_t)blockIdx.x * 256 + threadIdx.x) * 8;
    f32x4 x0 = *(const f32x4*)(in + i);
    f32x4 x1 = *(const f32x4*)(in + i + 4);
    bf16x8 v;
    v[0] = (bf16)x0[0]; v[1] = (bf16)x0[1]; v[2] = (bf16)x0[2]; v[3] = (bf16)x0[3];
    v[4] = (bf16)x1[0]; v[5] = (bf16)x1[1]; v[6] = (bf16)x1[2]; v[7] = (bf16)x1[3];
    *(bf16x8*)(out + i) = v;
}

__global__ __launch_bounds__(256) void pack_bias_kernel(
    const float* __restrict__ bq, const float* __restrict__ bk,
    const float* __restrict__ bv, const float* __restrict__ br,
    float* __restrict__ ball)
{
    const int i = blockIdx.x * 256 + threadIdx.x;  // 0..3583
    float v = (i < 1024) ? bq[i]
            : (i < 2048) ? bk[i - 1024]
            : (i < 3072) ? bv[i - 2048] : br[i - 3072];
    ball[i] = v;
}

// ---------------------------------------------------------------------------
// GEMM mainloop: BK=64, 4-buffer, counted-vmcnt pipeline.
//   buf[t&3]: A 128x64 (16KB) + B 128x64 (16KB).  LDS total 128KB.
//   iter t: STAGE(t+2) [8 loads] -> s_waitcnt vmcnt(16) [t's 8 landed,
//           t+1/t+2's 16 in flight] -> s_barrier -> compute(t).
//   Tail: t+2==nt -> vmcnt(8); t+1==nt -> vmcnt(0).
// Hazards: STAGE(t+2) overwrites buf[(t-2)&3]; its readers (compute(t-2))
// are TWO barriers back (end of iter t-2 and t-1) -> safe under 1-phase skew.
// LDS layout/swizzle identical to the round-4 BK=64 scheme that measured
// SQ_LDS_BANK_CONFLICT == 0: granule g stored at p=(row*8+j), j = g^(row&7).
// ---------------------------------------------------------------------------
__device__ __forceinline__ void gemm_mainloop_4x64(
    const bf16* __restrict__ A, const bf16* __restrict__ Wt,
    const int K, const int m0, const int n0, const int tid,
    bf16* SL, f32x4 (&acc)[4][4])
{
    const int lane = tid & 63;
    const int w = tid >> 6;
    const int wr = w >> 1, wc = w & 1;
    const int lr = lane & 15, lg = lane >> 4;
    const int nt = K >> 6;

    auto STAGE = [&](int t) {
        bf16* Ab = SL + (t & 3) * 8192;
        bf16* Bb = SL + 32768 + (t & 3) * 8192;
        const int k0 = t << 6;
#pragma unroll
        for (int i = 0; i < 4; i++) {
            const int p = i * 256 + tid;
            const int row = p >> 3;
            const int g = (p & 7) ^ (row & 7);     // inverse-swizzled source granule
            load_lds_16B(A + (size_t)(m0 + row) * K + k0 + g * 8, Ab + p * 8);
            load_lds_16B(Wt + (size_t)(n0 + row) * K + k0 + g * 8, Bb + p * 8);
        }
    };

    STAGE(0); STAGE(1);
    asm volatile("s_waitcnt vmcnt(8)" ::: "memory");   // tile 0 landed
    __builtin_amdgcn_s_barrier();

    for (int t = 0; t < nt; t++) {
        if (t + 2 < nt) {
            STAGE(t + 2);
            asm volatile("s_waitcnt vmcnt(16)" ::: "memory");  // tile t landed
        } else if (t + 1 < nt) {
            asm volatile("s_waitcnt vmcnt(8)" ::: "memory");
        } else {
            asm volatile("s_waitcnt vmcnt(0)" ::: "memory");
        }
        __builtin_amdgcn_s_barrier();

        const bf16* Ab = SL + (t & 3) * 8192;
        const bf16* Bb = SL + 32768 + (t & 3) * 8192;
#pragma unroll
        for (int kc = 0; kc < 2; kc++) {
            bf16x8 a[4], b[4];
#pragma unroll
            for (int mi = 0; mi < 4; mi++) {
                const int row = wr * 64 + mi * 16 + lr;
                a[mi] = *(const bf16x8*)&Ab[row * 64 + ((((kc << 2) | lg) ^ (row & 7)) << 3)];
            }
#pragma unroll
            for (int nj = 0; nj < 4; nj++) {
                const int row = wc * 64 + nj * 16 + lr;
                b[nj] = *(const bf16x8*)&Bb[row * 64 + ((((kc << 2) | lg) ^ (row & 7)) << 3)];
            }
            __builtin_amdgcn_s_setprio(1);
#pragma unroll
            for (int mi = 0; mi < 4; mi++)
#pragma unroll
                for (int nj = 0; nj < 4; nj++)
                    acc[mi][nj] = mfma16(a[mi], b[nj], acc[mi][nj]);
            __builtin_amdgcn_s_setprio(0);
        }
    }
    __builtin_amdgcn_s_barrier();   // SL free for epilogue reuse
}

// Epilogue helper: frags -> SL C-tile [128][136] -> coalesced bf16x8 stores.
template <int ACT>
__device__ __forceinline__ void epi_transpose_store(
    f32x4 (&acc)[4][4], const float* __restrict__ ball, bf16* SL,
    bf16* __restrict__ dst, const int pitch, const int m0, const int nglob0,
    const int nb, const float scale, const int tid)
{
    const int lane = tid & 63, w = tid >> 6;
    const int wr = w >> 1, wc = w & 1, lr = lane & 15, lg = lane >> 4;
#pragma unroll
    for (int mi = 0; mi < 4; mi++) {
#pragma unroll
        for (int nj = 0; nj < 4; nj++) {
            const float bn = ball[nglob0 + wc * 64 + nj * 16 + lr];
            const int rbase = wr * 64 + mi * 16 + lg * 4;
            const int cidx = wc * 64 + nj * 16 + lr;
#pragma unroll
            for (int r = 0; r < 4; r++) {
                float v = acc[mi][nj][r] + bn;
                if constexpr (ACT == 1) v = fmaxf(v, 0.f);
                SL[(rbase + r) * 136 + cidx] = (bf16)(v * scale);
            }
        }
    }
    __syncthreads();
#pragma unroll
    for (int pass = 0; pass < 4; pass++) {
        const int rr = pass * 32 + (tid >> 3);
        const int cc = (tid & 7) * 16;
        bf16x8 v0 = *(const bf16x8*)&SL[rr * 136 + cc];
        bf16x8 v1 = *(const bf16x8*)&SL[rr * 136 + cc + 8];
        *(bf16x8*)(dst + (size_t)(m0 + rr) * pitch + nb + cc) = v0;
        *(bf16x8*)(dst + (size_t)(m0 + rr) * pitch + nb + cc + 8) = v1;
    }
}

// Fused QKV+R GEMM: N=3584 (q relu*0.125 | k relu | v tanh transposed | r). K=512.
__global__ __launch_bounds__(256, 1) void gemm_qkvr_kernel(
    const bf16* __restrict__ A, const bf16* __restrict__ Wall,
    const float* __restrict__ ball,
    bf16* __restrict__ qc, bf16* __restrict__ kb, bf16* __restrict__ vt,
    bf16* __restrict__ resb)
{
    __shared__ bf16 SL[65536];   // 128KB: 4-buf staging, then C-tile
    const int tid = threadIdx.x;
    const int2 bc = swz_block();
    const int m0 = bc.y * 128, n0 = bc.x * 128;
    f32x4 acc[4][4];
    const f32x4 zero4 = {0.f, 0.f, 0.f, 0.f};
#pragma unroll
    for (int i = 0; i < 4; i++)
#pragma unroll
        for (int j = 0; j < 4; j++) acc[i][j] = zero4;

    gemm_mainloop_4x64(A, Wall, 512, m0, n0, tid, SL, acc);

    const int region = n0 >> 10;  // 0=q 1=k 2=v 3=r (128-tiles never straddle)
    if (region == 0) {
        epi_transpose_store<1>(acc, ball, SL, qc, 1024, m0, n0, n0 & 1023, 0.125f, tid);
    } else if (region == 1) {
        epi_transpose_store<1>(acc, ball, SL, kb, 1024, m0, n0, n0 & 1023, 1.f, tid);
    } else if (region == 3) {
        epi_transpose_store<0>(acc, ball, SL, resb, 512, m0, n0, n0 - 3072, 1.f, tid);
    } else {
        // v: tanh + per-head transposed store (8B-vectorized along t)
        const int lane = tid & 63, w = tid >> 6;
        const int wr = w >> 1, wc = w & 1, lr = lane & 15, lg = lane >> 4;
#pragma unroll
        for (int mi = 0; mi < 4; mi++) {
#pragma unroll
            for (int nj = 0; nj < 4; nj++) {
                const int n = n0 + wc * 64 + nj * 16 + lr;
                const float bn = ball[n];
                const int m = m0 + wr * 64 + mi * 16 + lg * 4;
                const int bb = m >> 9, t = m & 511;
                const int nn = n - 2048, hh = nn >> 6, f = nn & 63;
                bf16x4 st;
#pragma unroll
                for (int r = 0; r < 4; r++) st[r] = (bf16)fast_tanh(acc[mi][nj][r] + bn);
                *(bf16x4*)(vt + (((size_t)(bb * 16 + hh) * 64 + f) << 9) + t) = st;
            }
        }
    }
}

// Standard GEMM: N=512 pitch, bf16 out via LDS-transpose. ACT: 1 relu, 2 tanh.
template <int ACT>
__global__ __launch_bounds__(256, 1) void gemm_std_kernel(
    const bf16* __restrict__ A, const bf16* __restrict__ Wt,
    const float* __restrict__ bias, bf16* __restrict__ C, const int K)
{
    __shared__ bf16 SL[65536];
    const int tid = threadIdx.x;
    const int2 bc = swz_block();
    const int m0 = bc.y * 128, n0 = bc.x * 128;
    f32x4 acc[4][4];
    const f32x4 zero4 = {0.f, 0.f, 0.f, 0.f};
#pragma unroll
    for (int i = 0; i < 4; i++)
#pragma unroll
        for (int j = 0; j < 4; j++) acc[i][j] = zero4;

    gemm_mainloop_4x64(A, Wt, K, m0, n0, tid, SL, acc);

    const int lane = tid & 63, w = tid >> 6;
    const int wr = w >> 1, wc = w & 1, lr = lane & 15, lg = lane >> 4;
#pragma unroll
    for (int mi = 0; mi < 4; mi++) {
#pragma unroll
        for (int nj = 0; nj < 4; nj++) {
            const float bn = bias[n0 + wc * 64 + nj * 16 + lr];
            const int rbase = wr * 64 + mi * 16 + lg * 4;
            const int cidx = wc * 64 + nj * 16 + lr;
#pragma unroll
            for (int r = 0; r < 4; r++) {
                float v = acc[mi][nj][r] + bn;
                if constexpr (ACT == 1) v = fmaxf(v, 0.f);
                else if constexpr (ACT == 2) v = fast_tanh(v);
                SL[(rbase + r) * 136 + cidx] = (bf16)v;
            }
        }
    }
    __syncthreads();
#pragma unroll
    for (int pass = 0; pass < 4; pass++) {
        const int rr = pass * 32 + (tid >> 3);
        const int cc = (tid & 7) * 16;
        bf16x8 v0 = *(const bf16x8*)&SL[rr * 136 + cc];
        bf16x8 v1 = *(const bf16x8*)&SL[rr * 136 + cc + 8];
        *(bf16x8*)(C + (size_t)(m0 + rr) * 512 + n0 + cc) = v0;
        *(bf16x8*)(C + (size_t)(m0 + rr) * 512 + n0 + cc + 8) = v1;
    }
}

// ---------------------------------------------------------------------------
// MFMA flash attention, swapped-operand, reg-staged double-buffered K/V.
// Q arrives pre-scaled by 1/8 from the QKV GEMM.
// ---------------------------------------------------------------------------
static __device__ __forceinline__ int sigma_k(int t) {
    return (t & 32) | ((t & 4) << 2) | ((t & 24) >> 1) | (t & 3);
}

__global__ __launch_bounds__(256) void mfma_attn_kernel(
    const bf16* __restrict__ Kb, const bf16* __restrict__ Vt, bf16* __restrict__ QC)
{
    __shared__ bf16 Ks[2][64][72];
    __shared__ bf16 Vts[2][64][72];

    int l = blockIdx.x;
    l = (l & 7) * 256 + (l >> 3);      // XCD chunk swizzle
    const int qb = l & 3;
    const int h = (l >> 2) & 15;
    const int b = l >> 6;
    const int tid = threadIdx.x;
    const int lane = tid & 63;
    const int w = tid >> 6;
    const int lr = lane & 15, lg = lane >> 4;

    const int qrow0 = qb * 128 + w * 32;
    const size_t qbase = ((size_t)b * T_ + qrow0) * NQ_ + h * 64;
    const int bh = b * HN_ + h;

    // Q fragments (B-frag: col q=lr, k=f) -- read before any QC write
    bf16x8 qf[2][2];
#pragma unroll
    for (int mi = 0; mi < 2; mi++)
#pragma unroll
        for (int kc = 0; kc < 2; kc++)
            qf[mi][kc] = *(const bf16x8*)(QC + qbase + (size_t)(mi * 16 + lr) * NQ_ + kc * 32 + lg * 8);

    const f32x4 zero4 = {0.f, 0.f, 0.f, 0.f};
    f32x4 o[2][4];
    float m_st[2] = {-1e30f, -1e30f}, l_st[2] = {0.f, 0.f};
#pragma unroll
    for (int mi = 0; mi < 2; mi++)
#pragma unroll
        for (int dj = 0; dj < 4; dj++) o[mi][dj] = zero4;

    const int nsb = 2 * qb + 2;

    bf16x8 kreg[2], vreg[2];
    auto LOADR = [&](int sb) {
#pragma unroll
        for (int i = 0; i < 2; i++) {
            const int ci = i * 256 + tid, row = ci >> 3, cc = ci & 7;
            kreg[i] = *(const bf16x8*)(Kb + ((size_t)b * T_ + sb * 64 + row) * NQ_ + h * 64 + cc * 8);
            vreg[i] = *(const bf16x8*)(Vt + ((size_t)bh * 64 + row) * T_ + sb * 64 + cc * 8);
        }
    };
    auto WRITE = [&](int buf) {
#pragma unroll
        for (int i = 0; i < 2; i++) {
            const int ci = i * 256 + tid, row = ci >> 3, cc = ci & 7;
            *(bf16x8*)&Ks[buf][sigma_k(row)][cc * 8] = kreg[i];
            *(bf16x8*)&Vts[buf][row][cc * 8] = vreg[i];
        }
    };

    LOADR(0); WRITE(0); __syncthreads();
    int cur = 0;

    for (int sb = 0; sb < nsb; sb++) {
        const bool pf = (sb + 1 < nsb);
        if (pf) LOADR(sb + 1);          // in flight during compute (T14)

        if (sb * 64 <= qrow0 + 31) {    // wave has unmasked work (wave-uniform)
            // S^T = K Q^T
            f32x4 sc[2][4];
#pragma unroll
            for (int mi = 0; mi < 2; mi++)
#pragma unroll
                for (int nj = 0; nj < 4; nj++) sc[mi][nj] = zero4;
            __builtin_amdgcn_s_setprio(1);
#pragma unroll
            for (int kc = 0; kc < 2; kc++) {
                bf16x8 kf[4];
#pragma unroll
                for (int nj = 0; nj < 4; nj++)
                    kf[nj] = *(const bf16x8*)&Ks[cur][nj * 16 + lr][kc * 32 + lg * 8];
#pragma unroll
                for (int mi = 0; mi < 2; mi++)
#pragma unroll
                    for (int nj = 0; nj < 4; nj++)
                        sc[mi][nj] = mfma16(kf[nj], qf[mi][kc], sc[mi][nj]);
            }
            __builtin_amdgcn_s_setprio(0);
            // causal mask + in-register row max (q pre-scaled by 1/8)
            const bool needmask = (sb * 64 + 63 > qrow0);
            float tm[2];
#pragma unroll
            for (int mi = 0; mi < 2; mi++) {
                const int qg = qrow0 + mi * 16 + lr;
                float mx = -1e30f;
#pragma unroll
                for (int nj = 0; nj < 4; nj++) {
                    const int kvb = sb * 64 + ((nj >> 1) << 5) + ((nj & 1) << 2) + lg * 8;
#pragma unroll
                    for (int r = 0; r < 4; r++) {
                        float s = sc[mi][nj][r];
                        if (needmask && (kvb + r > qg)) s = -1e30f;
                        sc[mi][nj][r] = s;
                        mx = fmaxf(mx, s);
                    }
                }
                mx = fmaxf(mx, __shfl_xor(mx, 16));
                mx = fmaxf(mx, __shfl_xor(mx, 32));
                tm[mi] = mx;
            }
            // defer-max (T13)
            const bool defer = (tm[0] <= m_st[0] + 8.f) && (tm[1] <= m_st[1] + 8.f);
            if (!__all(defer)) {
#pragma unroll
                for (int mi = 0; mi < 2; mi++) {
                    const float mn = fmaxf(m_st[mi], tm[mi]);
                    const float sf = __expf(m_st[mi] - mn);
                    m_st[mi] = mn;
                    l_st[mi] *= sf;
#pragma unroll
                    for (int dj = 0; dj < 4; dj++)
#pragma unroll
                        for (int r = 0; r < 4; r++) o[mi][dj][r] *= sf;
                }
            }
            // P = exp(S - m), row-sum, pack (already PV B-frag order)
            bf16x4 pk[2][4];
#pragma unroll
            for (int mi = 0; mi < 2; mi++) {
                float ts = 0.f;
#pragma unroll
                for (int nj = 0; nj < 4; nj++)
#pragma unroll
                    for (int r = 0; r < 4; r++) {
                        const float p = __expf(sc[mi][nj][r] - m_st[mi]);
                        ts += p;
                        pk[mi][nj][r] = (bf16)p;
                    }
                ts += __shfl_xor(ts, 16);
                ts += __shfl_xor(ts, 32);
                l_st[mi] += ts;
            }
            // O^T += V^T P^T
            __builtin_amdgcn_s_setprio(1);
#pragma unroll
            for (int kc = 0; kc < 2; kc++) {
                bf16x8 vf[4], pf2[2];
#pragma unroll
                for (int mi = 0; mi < 2; mi++) {
                    bf16x8 t;
#pragma unroll
                    for (int r = 0; r < 4; r++) { t[r] = pk[mi][2 * kc][r]; t[r + 4] = pk[mi][2 * kc + 1][r]; }
                    pf2[mi] = t;
                }
#pragma unroll
                for (int dj = 0; dj < 4; dj++)
                    vf[dj] = *(const bf16x8*)&Vts[cur][dj * 16 + lr][kc * 32 + lg * 8];
#pragma unroll
                for (int mi = 0; mi < 2; mi++)
#pragma unroll
                    for (int dj = 0; dj < 4; dj++)
                        o[mi][dj] = mfma16(vf[dj], pf2[mi], o[mi][dj]);
            }
            __builtin_amdgcn_s_setprio(0);
        }

        if (pf) WRITE(cur ^ 1);          // overwrite target's readers fenced at sb-1
        __syncthreads();                 // writes visible; single barrier per iter
        cur ^= 1;
    }

    // normalize + in-place store (O^T: lane owns q=lr col, d=lg*4+r rows)
#pragma unroll
    for (int mi = 0; mi < 2; mi++) {
        const float inv = 1.f / l_st[mi];
        const size_t rowoff = qbase + (size_t)(mi * 16 + lr) * NQ_;
#pragma unroll
        for (int dj = 0; dj < 4; dj++) {
            bf16x4 st;
#pragma unroll
            for (int r = 0; r < 4; r++) st[r] = (bf16)(o[mi][dj][r] * inv);
            *(bf16x4*)(QC + rowoff + dj * 16 + lg * 4) = st;
        }
    }
}

// ---------------------------------------------------------------------------
// LayerNorm, one 64-lane wave per 512-wide row, bf16x8 loads.
// ---------------------------------------------------------------------------
template <bool F32OUT>
__global__ __launch_bounds__(256) void ln_kernel(
    const bf16* __restrict__ xa, const bf16* __restrict__ xb,
    const float* __restrict__ w, const float* __restrict__ bias,
    void* __restrict__ outv)
{
    const int row = blockIdx.x * 4 + (threadIdx.x >> 6);
    const int ln = threadIdx.x & 63;
    const size_t base = (size_t)row * 512 + ln * 8;
    const bf16x8 va = *(const bf16x8*)(xa + base);
    const bf16x8 vb = *(const bf16x8*)(xb + base);
    float x[8];
    float s = 0.f;
#pragma unroll
    for (int i = 0; i < 8; i++) { x[i] = (float)va[i] + (float)vb[i]; s += x[i]; }
#pragma unroll
    for (int off = 32; off >= 1; off >>= 1) s += __shfl_xor(s, off);
    const float mean = s * (1.f / 512.f);
    float ss = 0.f;
#pragma unroll
    for (int i = 0; i < 8; i++) { x[i] -= mean; ss += x[i] * x[i]; }
#pragma unroll
    for (int off = 32; off >= 1; off >>= 1) ss += __shfl_xor(ss, off);
    const float inv = rsqrtf(ss * (1.f / 512.f) + 1e-5f);
    const f32x4 w0 = *(const f32x4*)(w + ln * 8);
    const f32x4 w1 = *(const f32x4*)(w + ln * 8 + 4);
    const f32x4 b0 = *(const f32x4*)(bias + ln * 8);
    const f32x4 b1 = *(const f32x4*)(bias + ln * 8 + 4);
    if constexpr (F32OUT) {
        f32x4 y0, y1;
#pragma unroll
        for (int i = 0; i < 4; i++) {
            y0[i] = x[i] * inv * w0[i] + b0[i];
            y1[i] = x[4 + i] * inv * w1[i] + b1[i];
        }
        *(f32x4*)((float*)outv + base) = y0;
        *(f32x4*)((float*)outv + base + 4) = y1;
    } else {
        bf16x8 y;
#pragma unroll
        for (int i = 0; i < 4; i++) {
            y[i] = (bf16)(x[i] * inv * w0[i] + b0[i]);
            y[4 + i] = (bf16)(x[4 + i] * inv * w1[i] + b1[i]);
        }
        *(bf16x8*)((bf16*)outv + base) = y;
    }
}

// ---------------------------------------------------------------------------
extern "C" void kernel_launch(void* const* d_in, const int* in_sizes, int n_in,
                              void* d_out, int out_size, void* d_ws, size_t ws_size,
                              hipStream_t stream)
{
    const float* inputs = (const float*)d_in[0];
    const float* Wq = (const float*)d_in[1];
    const float* bq = (const float*)d_in[2];
    const float* Wk = (const float*)d_in[3];
    const float* bk = (const float*)d_in[4];
    const float* Wv = (const float*)d_in[5];
    const float* bv = (const float*)d_in[6];
    const float* Wr = (const float*)d_in[7];
    const float* br = (const float*)d_in[8];
    const float* Wo = (const float*)d_in[9];
    const float* bo = (const float*)d_in[10];
    const float* ln1w = (const float*)d_in[11];
    const float* ln1b = (const float*)d_in[12];
    const float* Wfc = (const float*)d_in[13];
    const float* bfc = (const float*)d_in[14];
    const float* ln2w = (const float*)d_in[15];
    const float* ln2b = (const float*)d_in[16];
    float* out = (float*)d_out;

    // Workspace layout (~117 MB):
    const size_t MB = 1024ull * 1024ull;
    char* ws = (char*)d_ws;
    bf16* qc   = (bf16*)(ws);               // 32MB [M][1024] q -> attn out (in place)
    bf16* kb   = (bf16*)(ws + 32 * MB);     // 32MB [M][1024] k; post-attn: att|ln1
    bf16* vt   = (bf16*)(ws + 64 * MB);     // 32MB v^T; post-attn: fcb
    bf16* xin  = (bf16*)(ws + 96 * MB);     // 16MB bf16 inputs
    bf16* wall = (bf16*)(ws + 112 * MB);    // 3.5MB [3584][512] Wq|Wk|Wv|Wr
    bf16* wot  = (bf16*)(ws + 112 * MB + 3670016);            // 1MB [512][1024]
    bf16* wfct = (bf16*)(ws + 112 * MB + 3670016 + 1048576);  // 0.5MB [512][512]
    float* ball = (float*)(ws + 112 * MB + 3670016 + 1048576 + 524288);  // 14KB
    bf16* wrt  = wall + (size_t)3072 * 512;
    bf16* resb = (bf16*)d_out;              // residual in d_out's spare bytes
    bf16* att  = kb;                        // 16MB (kb dead after attention)
    bf16* ln1  = kb + (size_t)8 * MB;       // 16MB (second half of kb)
    bf16* fcb  = vt;                        // 16MB (vt dead after attention)

    const dim3 blk(256);

    // prep
    conv_input_kernel<<<dim3(4096), blk, 0, stream>>>(inputs, xin);
    prep_headw_kernel<<<dim3(384), blk, 0, stream>>>(Wq, Wk, Wv, wall);
    prep_plain_kernel<<<dim3(256), blk, 0, stream>>>(Wr, Wo, Wfc, wrt, wot, wfct);
    pack_bias_kernel<<<dim3(14), blk, 0, stream>>>(bq, bk, bv, br, ball);

    // fused QKV + residual projection (N=3584)
    gemm_qkvr_kernel<<<dim3(28, 128), blk, 0, stream>>>(xin, wall, ball, qc, kb, vt, resb);
    // attention (in place over qc)
    mfma_attn_kernel<<<dim3(B_ * HN_ * 4), blk, 0, stream>>>(kb, vt, qc);
    // att = tanh(concat @ Wo + bo)
    gemm_std_kernel<2><<<dim3(4, 128), blk, 0, stream>>>(qc, wot, bo, att, 1024);
    // ln1 = LN1(att + resb)
    ln_kernel<false><<<dim3(4096), blk, 0, stream>>>(att, resb, ln1w, ln1b, ln1);
    // fcb = relu(ln1 @ Wfc + bfc)
    gemm_std_kernel<1><<<dim3(4, 128), blk, 0, stream>>>(ln1, wfct, bfc, fcb, 512);
    // out = LN2(fcb + ln1)  (f32 final)
    ln_kernel<true ><<<dim3(4096), blk, 0, stream>>>(fcb, ln1, ln2w, ln2b, out);
}

// Round 7
// 241.465 us; speedup vs baseline: 1.1143x; 1.1143x over previous
//
#include <hip/hip_runtime.h>
#include <hip/hip_bf16.h>

// Problem constants
#define B_  32
#define T_  512
#define D_  512
#define HD_ 64
#define HN_ 16
#define O_  512
#define M_  (B_ * T_)      // 16384 rows
#define NQ_ (HN_ * HD_)    // 1024 qkv cols

typedef __bf16 bf16;
typedef __attribute__((ext_vector_type(8))) __bf16 bf16x8;
typedef __attribute__((ext_vector_type(4))) __bf16 bf16x4;
typedef __attribute__((ext_vector_type(4))) float f32x4;

static __device__ __forceinline__ f32x4 mfma16(bf16x8 a, bf16x8 b, f32x4 c) {
    return __builtin_amdgcn_mfma_f32_16x16x32_bf16(a, b, c, 0, 0, 0);
}

// Direct global->LDS 16B copy.
static __device__ __forceinline__ void load_lds_16B(const bf16* g, bf16* l) {
    __builtin_amdgcn_global_load_lds(
        (const __attribute__((address_space(1))) unsigned int*)(unsigned long long)g,
        (__attribute__((address_space(3))) unsigned int*)(unsigned long long)l,
        16, 0, 0);
}

static __device__ __forceinline__ float fast_tanh(float x) {
    return 1.f - 2.f / (__expf(2.f * x) + 1.f);
}

// T1 chunked XCD swizzle: requires (gridDim.x*gridDim.y) % 8 == 0.
static __device__ __forceinline__ int2 swz_block() {
    const int nx = gridDim.x;
    const int nwg = nx * gridDim.y;
    int l = blockIdx.y * nx + blockIdx.x;
    l = (l & 7) * (nwg >> 3) + (l >> 3);
    return make_int2(l % nx, l / nx);
}

// ---------------------------------------------------------------------------
// Fused prep: conv_input (4096 blocks) | headw (384) | plain (256) | bias (14).
// ---------------------------------------------------------------------------
__global__ __launch_bounds__(256) void prep_all_kernel(
    const float* __restrict__ inputs,
    const float* __restrict__ Wq, const float* __restrict__ Wk,
    const float* __restrict__ Wv, const float* __restrict__ Wr,
    const float* __restrict__ Wo, const float* __restrict__ Wfc,
    const float* __restrict__ bq, const float* __restrict__ bk,
    const float* __restrict__ bv, const float* __restrict__ br,
    bf16* __restrict__ xin, bf16* __restrict__ wall,
    bf16* __restrict__ wrt, bf16* __restrict__ wot, bf16* __restrict__ wfct,
    float* __restrict__ ball)
{
    __shared__ bf16 tl[64][72];
    const int tid = threadIdx.x;
    int id = blockIdx.x;

    if (id < 4096) {
        // f32 -> bf16 input conversion
        const size_t i = ((size_t)id * 256 + tid) * 8;
        f32x4 x0 = *(const f32x4*)(inputs + i);
        f32x4 x1 = *(const f32x4*)(inputs + i + 4);
        bf16x8 v;
        v[0] = (bf16)x0[0]; v[1] = (bf16)x0[1]; v[2] = (bf16)x0[2]; v[3] = (bf16)x0[3];
        v[4] = (bf16)x1[0]; v[5] = (bf16)x1[1]; v[6] = (bf16)x1[2]; v[7] = (bf16)x1[3];
        *(bf16x8*)(xin + i) = v;
        return;
    }
    if (id < 4480) {
        // head weights [HN][K][64] -> wall [h*64+f][512]
        id -= 4096;
        const int kt = id & 7; id >>= 3;
        const int h = id & 15; id >>= 4;
        const float* src = (id == 0) ? Wq : (id == 1) ? Wk : Wv;
        bf16* dst = wall + (size_t)id * (1024 * 512);
        const int k0 = kt * 64;
#pragma unroll
        for (int i = 0; i < 4; i++) {
            const int e = i * 256 + tid;
            const int kk = e >> 4, f4 = (e & 15) * 4;
            const f32x4 v = *(const f32x4*)(src + ((size_t)h * 512 + k0 + kk) * 64 + f4);
#pragma unroll
            for (int j = 0; j < 4; j++) tl[f4 + j][kk] = (bf16)v[j];
        }
        __syncthreads();
#pragma unroll
        for (int i = 0; i < 2; i++) {
            const int e = i * 256 + tid;
            const int f = e >> 3, kc = (e & 7) * 8;
            *(bf16x8*)(dst + ((size_t)h * 64 + f) * 512 + k0 + kc) = *(const bf16x8*)&tl[f][kc];
        }
        return;
    }
    if (id < 4736) {
        // plain weights [K][N] -> [N][K]
        id -= 4480;
        const float* src; bf16* dst; int K;
        if (id < 64)       { src = Wr;  dst = wrt;  K = 512;  }
        else if (id < 192) { src = Wo;  dst = wot;  K = 1024; id -= 64; }
        else               { src = Wfc; dst = wfct; K = 512;  id -= 192; }
        const int kt = id >> 3, nt = id & 7;
        const int k0 = kt * 64, n0 = nt * 64;
#pragma unroll
        for (int i = 0; i < 4; i++) {
            const int e = i * 256 + tid;
            const int kk = e >> 4, n4 = (e & 15) * 4;
            const f32x4 v = *(const f32x4*)(src + (size_t)(k0 + kk) * 512 + n0 + n4);
#pragma unroll
            for (int j = 0; j < 4; j++) tl[n4 + j][kk] = (bf16)v[j];
        }
        __syncthreads();
#pragma unroll
        for (int i = 0; i < 2; i++) {
            const int e = i * 256 + tid;
            const int nn = e >> 3, kc = (e & 7) * 8;
            *(bf16x8*)(dst + (size_t)(n0 + nn) * K + k0 + kc) = *(const bf16x8*)&tl[nn][kc];
        }
        return;
    }
    // bias pack (14 blocks)
    const int i = (id - 4736) * 256 + tid;  // 0..3583
    float v = (i < 1024) ? bq[i]
            : (i < 2048) ? bk[i - 1024]
            : (i < 3072) ? bv[i - 2048] : br[i - 3072];
    ball[i] = v;
}

// ---------------------------------------------------------------------------
// GEMM mainloop: 4-buffer BK=32 counted-vmcnt pipeline (r5 schedule) +
// granule swizzle (fixes r5's 8-way conflict):
//   LDS slot (row r, s) holds global granule g = s ^ ((r>>1)&3)  (involution).
//   Read side: frag slot = lg ^ ((row>>1)&3).
//   Bank check: 16-lane group (rows r..r+15, lg fixed) -> 8 distinct bank-
//   quads (row&1 x (row>>1)&3), 2 rows/quad -> 2-way = free.
// Schedule per iter t: STAGE(t+2)[4 loads] -> vmcnt(4) [tile t+1 landed,
//   t+2 in flight] -> s_barrier -> compute(t) [16 MFMA].
// buf distance 4: STAGE(t+2) overwrites buf[(t-2)&3], readers two barriers
// back (verified correct in r5). LDS = 64KB -> 2 blocks/CU.
// ---------------------------------------------------------------------------
__device__ __forceinline__ void gemm_mainloop_p4(
    const bf16* __restrict__ A, const bf16* __restrict__ Wt,
    const int K, const int m0, const int n0, const int tid,
    bf16* SL, f32x4 (&acc)[4][4])
{
    const int lane = tid & 63;
    const int w = tid >> 6;
    const int wr = w >> 1, wc = w & 1;
    const int lr = lane & 15, lg = lane >> 4;
    const int nt = K >> 5;

    // staging: slot p0 = tid (rows 0..63), p1 = tid+256 (rows 64..127)
    const int r0 = tid >> 2, s0 = tid & 3;
    const int g0 = s0 ^ ((r0 >> 1) & 3);       // source granule (inverse swz)
    const int r1 = r0 + 64;
    const int g1 = s0 ^ ((r1 >> 1) & 3);
    const bf16* aS0 = A + (size_t)(m0 + r0) * K + g0 * 8;
    const bf16* aS1 = A + (size_t)(m0 + r1) * K + g1 * 8;
    const bf16* bS0 = Wt + (size_t)(n0 + r0) * K + g0 * 8;
    const bf16* bS1 = Wt + (size_t)(n0 + r1) * K + g1 * 8;

    auto STAGE = [&](int t) {
        bf16* Ab = SL + (t & 3) * 4096;
        bf16* Bb = SL + 16384 + (t & 3) * 4096;
        const int k0 = t << 5;
        load_lds_16B(aS0 + k0, Ab + tid * 8);
        load_lds_16B(aS1 + k0, Ab + (tid + 256) * 8);
        load_lds_16B(bS0 + k0, Bb + tid * 8);
        load_lds_16B(bS1 + k0, Bb + (tid + 256) * 8);
    };

    STAGE(0); STAGE(1);
    asm volatile("s_waitcnt vmcnt(4)" ::: "memory");   // tile 0 landed
    __builtin_amdgcn_s_barrier();

    for (int t = 0; t < nt; t++) {
        if (t + 2 < nt) {
            STAGE(t + 2);
            asm volatile("s_waitcnt vmcnt(4)" ::: "memory");  // tile t+1 landed
        } else {
            asm volatile("s_waitcnt vmcnt(0)" ::: "memory");
        }
        __builtin_amdgcn_s_barrier();

        const bf16* Ab = SL + (t & 3) * 4096;
        const bf16* Bb = SL + 16384 + (t & 3) * 4096;
        bf16x8 a[4], b[4];
#pragma unroll
        for (int mi = 0; mi < 4; mi++) {
            const int row = wr * 64 + mi * 16 + lr;
            a[mi] = *(const bf16x8*)&Ab[row * 32 + ((lg ^ ((row >> 1) & 3)) << 3)];
        }
#pragma unroll
        for (int nj = 0; nj < 4; nj++) {
            const int row = wc * 64 + nj * 16 + lr;
            b[nj] = *(const bf16x8*)&Bb[row * 32 + ((lg ^ ((row >> 1) & 3)) << 3)];
        }
        __builtin_amdgcn_s_setprio(1);
#pragma unroll
        for (int mi = 0; mi < 4; mi++)
#pragma unroll
            for (int nj = 0; nj < 4; nj++)
                acc[mi][nj] = mfma16(a[mi], b[nj], acc[mi][nj]);
        __builtin_amdgcn_s_setprio(0);
    }
    __builtin_amdgcn_s_barrier();   // SL free for epilogue reuse
}

// Epilogue helper: frags -> SL C-tile [128][136] -> coalesced bf16x8 stores.
template <int ACT>
__device__ __forceinline__ void epi_transpose_store(
    f32x4 (&acc)[4][4], const float* __restrict__ ball, bf16* SL,
    bf16* __restrict__ dst, const int pitch, const int m0, const int nglob0,
    const int nb, const float scale, const int tid)
{
    const int lane = tid & 63, w = tid >> 6;
    const int wr = w >> 1, wc = w & 1, lr = lane & 15, lg = lane >> 4;
#pragma unroll
    for (int mi = 0; mi < 4; mi++) {
#pragma unroll
        for (int nj = 0; nj < 4; nj++) {
            const float bn = ball[nglob0 + wc * 64 + nj * 16 + lr];
            const int rbase = wr * 64 + mi * 16 + lg * 4;
            const int cidx = wc * 64 + nj * 16 + lr;
#pragma unroll
            for (int r = 0; r < 4; r++) {
                float v = acc[mi][nj][r] + bn;
                if constexpr (ACT == 1) v = fmaxf(v, 0.f);
                SL[(rbase + r) * 136 + cidx] = (bf16)(v * scale);
            }
        }
    }
    __syncthreads();
#pragma unroll
    for (int pass = 0; pass < 4; pass++) {
        const int rr = pass * 32 + (tid >> 3);
        const int cc = (tid & 7) * 16;
        bf16x8 v0 = *(const bf16x8*)&SL[rr * 136 + cc];
        bf16x8 v1 = *(const bf16x8*)&SL[rr * 136 + cc + 8];
        *(bf16x8*)(dst + (size_t)(m0 + rr) * pitch + nb + cc) = v0;
        *(bf16x8*)(dst + (size_t)(m0 + rr) * pitch + nb + cc + 8) = v1;
    }
}

// Fused QKV+R GEMM: N=3584 (q relu*0.125 | k relu | v tanh transposed | r). K=512.
__global__ __launch_bounds__(256) void gemm_qkvr_kernel(
    const bf16* __restrict__ A, const bf16* __restrict__ Wall,
    const float* __restrict__ ball,
    bf16* __restrict__ qc, bf16* __restrict__ kb, bf16* __restrict__ vt,
    bf16* __restrict__ resb)
{
    __shared__ bf16 SL[32768];   // 64KB: 4-buf staging, then C-tile
    const int tid = threadIdx.x;
    const int2 bc = swz_block();
    const int m0 = bc.y * 128, n0 = bc.x * 128;
    f32x4 acc[4][4];
    const f32x4 zero4 = {0.f, 0.f, 0.f, 0.f};
#pragma unroll
    for (int i = 0; i < 4; i++)
#pragma unroll
        for (int j = 0; j < 4; j++) acc[i][j] = zero4;

    gemm_mainloop_p4(A, Wall, 512, m0, n0, tid, SL, acc);

    const int region = n0 >> 10;  // 0=q 1=k 2=v 3=r (128-tiles never straddle)
    if (region == 0) {
        epi_transpose_store<1>(acc, ball, SL, qc, 1024, m0, n0, n0 & 1023, 0.125f, tid);
    } else if (region == 1) {
        epi_transpose_store<1>(acc, ball, SL, kb, 1024, m0, n0, n0 & 1023, 1.f, tid);
    } else if (region == 3) {
        epi_transpose_store<0>(acc, ball, SL, resb, 512, m0, n0, n0 - 3072, 1.f, tid);
    } else {
        // v: tanh + per-head transposed store (8B-vectorized along t)
        const int lane = tid & 63, w = tid >> 6;
        const int wr = w >> 1, wc = w & 1, lr = lane & 15, lg = lane >> 4;
#pragma unroll
        for (int mi = 0; mi < 4; mi++) {
#pragma unroll
            for (int nj = 0; nj < 4; nj++) {
                const int n = n0 + wc * 64 + nj * 16 + lr;
                const float bn = ball[n];
                const int m = m0 + wr * 64 + mi * 16 + lg * 4;
                const int bb = m >> 9, t = m & 511;
                const int nn = n - 2048, hh = nn >> 6, f = nn & 63;
                bf16x4 st;
#pragma unroll
                for (int r = 0; r < 4; r++) st[r] = (bf16)fast_tanh(acc[mi][nj][r] + bn);
                *(bf16x4*)(vt + (((size_t)(bb * 16 + hh) * 64 + f) << 9) + t) = st;
            }
        }
    }
}

// Standard GEMM: N=512 pitch, bf16 out via LDS-transpose. ACT: 1 relu, 2 tanh.
template <int ACT>
__global__ __launch_bounds__(256) void gemm_std_kernel(
    const bf16* __restrict__ A, const bf16* __restrict__ Wt,
    const float* __restrict__ bias, bf16* __restrict__ C, const int K)
{
    __shared__ bf16 SL[32768];
    const int tid = threadIdx.x;
    const int2 bc = swz_block();
    const int m0 = bc.y * 128, n0 = bc.x * 128;
    f32x4 acc[4][4];
    const f32x4 zero4 = {0.f, 0.f, 0.f, 0.f};
#pragma unroll
    for (int i = 0; i < 4; i++)
#pragma unroll
        for (int j = 0; j < 4; j++) acc[i][j] = zero4;

    gemm_mainloop_p4(A, Wt, K, m0, n0, tid, SL, acc);

    const int lane = tid & 63, w = tid >> 6;
    const int wr = w >> 1, wc = w & 1, lr = lane & 15, lg = lane >> 4;
#pragma unroll
    for (int mi = 0; mi < 4; mi++) {
#pragma unroll
        for (int nj = 0; nj < 4; nj++) {
            const float bn = bias[n0 + wc * 64 + nj * 16 + lr];
            const int rbase = wr * 64 + mi * 16 + lg * 4;
            const int cidx = wc * 64 + nj * 16 + lr;
#pragma unroll
            for (int r = 0; r < 4; r++) {
                float v = acc[mi][nj][r] + bn;
                if constexpr (ACT == 1) v = fmaxf(v, 0.f);
                else if constexpr (ACT == 2) v = fast_tanh(v);
                SL[(rbase + r) * 136 + cidx] = (bf16)v;
            }
        }
    }
    __syncthreads();
#pragma unroll
    for (int pass = 0; pass < 4; pass++) {
        const int rr = pass * 32 + (tid >> 3);
        const int cc = (tid & 7) * 16;
        bf16x8 v0 = *(const bf16x8*)&SL[rr * 136 + cc];
        bf16x8 v1 = *(const bf16x8*)&SL[rr * 136 + cc + 8];
        *(bf16x8*)(C + (size_t)(m0 + rr) * 512 + n0 + cc) = v0;
        *(bf16x8*)(C + (size_t)(m0 + rr) * 512 + n0 + cc + 8) = v1;
    }
}

// ---------------------------------------------------------------------------
// MFMA flash attention, swapped-operand, reg-staged double-buffered K/V.
// Q arrives pre-scaled by 1/8 from the QKV GEMM.  (unchanged from r4/r5)
// ---------------------------------------------------------------------------
static __device__ __forceinline__ int sigma_k(int t) {
    return (t & 32) | ((t & 4) << 2) | ((t & 24) >> 1) | (t & 3);
}

__global__ __launch_bounds__(256) void mfma_attn_kernel(
    const bf16* __restrict__ Kb, const bf16* __restrict__ Vt, bf16* __restrict__ QC)
{
    __shared__ bf16 Ks[2][64][72];
    __shared__ bf16 Vts[2][64][72];

    int l = blockIdx.x;
    l = (l & 7) * 256 + (l >> 3);      // XCD chunk swizzle
    const int qb = l & 3;
    const int h = (l >> 2) & 15;
    const int b = l >> 6;
    const int tid = threadIdx.x;
    const int lane = tid & 63;
    const int w = tid >> 6;
    const int lr = lane & 15, lg = lane >> 4;

    const int qrow0 = qb * 128 + w * 32;
    const size_t qbase = ((size_t)b * T_ + qrow0) * NQ_ + h * 64;
    const int bh = b * HN_ + h;

    // Q fragments (B-frag: col q=lr, k=f) -- read before any QC write
    bf16x8 qf[2][2];
#pragma unroll
    for (int mi = 0; mi < 2; mi++)
#pragma unroll
        for (int kc = 0; kc < 2; kc++)
            qf[mi][kc] = *(const bf16x8*)(QC + qbase + (size_t)(mi * 16 + lr) * NQ_ + kc * 32 + lg * 8);

    const f32x4 zero4 = {0.f, 0.f, 0.f, 0.f};
    f32x4 o[2][4];
    float m_st[2] = {-1e30f, -1e30f}, l_st[2] = {0.f, 0.f};
#pragma unroll
    for (int mi = 0; mi < 2; mi++)
#pragma unroll
        for (int dj = 0; dj < 4; dj++) o[mi][dj] = zero4;

    const int nsb = 2 * qb + 2;

    bf16x8 kreg[2], vreg[2];
    auto LOADR = [&](int sb) {
#pragma unroll
        for (int i = 0; i < 2; i++) {
            const int ci = i * 256 + tid, row = ci >> 3, cc = ci & 7;
            kreg[i] = *(const bf16x8*)(Kb + ((size_t)b * T_ + sb * 64 + row) * NQ_ + h * 64 + cc * 8);
            vreg[i] = *(const bf16x8*)(Vt + ((size_t)bh * 64 + row) * T_ + sb * 64 + cc * 8);
        }
    };
    auto WRITE = [&](int buf) {
#pragma unroll
        for (int i = 0; i < 2; i++) {
            const int ci = i * 256 + tid, row = ci >> 3, cc = ci & 7;
            *(bf16x8*)&Ks[buf][sigma_k(row)][cc * 8] = kreg[i];
            *(bf16x8*)&Vts[buf][row][cc * 8] = vreg[i];
        }
    };

    LOADR(0); WRITE(0); __syncthreads();
    int cur = 0;

    for (int sb = 0; sb < nsb; sb++) {
        const bool pf = (sb + 1 < nsb);
        if (pf) LOADR(sb + 1);          // in flight during compute (T14)

        if (sb * 64 <= qrow0 + 31) {    // wave has unmasked work (wave-uniform)
            // S^T = K Q^T
            f32x4 sc[2][4];
#pragma unroll
            for (int mi = 0; mi < 2; mi++)
#pragma unroll
                for (int nj = 0; nj < 4; nj++) sc[mi][nj] = zero4;
            __builtin_amdgcn_s_setprio(1);
#pragma unroll
            for (int kc = 0; kc < 2; kc++) {
                bf16x8 kf[4];
#pragma unroll
                for (int nj = 0; nj < 4; nj++)
                    kf[nj] = *(const bf16x8*)&Ks[cur][nj * 16 + lr][kc * 32 + lg * 8];
#pragma unroll
                for (int mi = 0; mi < 2; mi++)
#pragma unroll
                    for (int nj = 0; nj < 4; nj++)
                        sc[mi][nj] = mfma16(kf[nj], qf[mi][kc], sc[mi][nj]);
            }
            __builtin_amdgcn_s_setprio(0);
            // causal mask + in-register row max (q pre-scaled by 1/8)
            const bool needmask = (sb * 64 + 63 > qrow0);
            float tm[2];
#pragma unroll
            for (int mi = 0; mi < 2; mi++) {
                const int qg = qrow0 + mi * 16 + lr;
                float mx = -1e30f;
#pragma unroll
                for (int nj = 0; nj < 4; nj++) {
                    const int kvb = sb * 64 + ((nj >> 1) << 5) + ((nj & 1) << 2) + lg * 8;
#pragma unroll
                    for (int r = 0; r < 4; r++) {
                        float s = sc[mi][nj][r];
                        if (needmask && (kvb + r > qg)) s = -1e30f;
                        sc[mi][nj][r] = s;
                        mx = fmaxf(mx, s);
                    }
                }
                mx = fmaxf(mx, __shfl_xor(mx, 16));
                mx = fmaxf(mx, __shfl_xor(mx, 32));
                tm[mi] = mx;
            }
            // defer-max (T13)
            const bool defer = (tm[0] <= m_st[0] + 8.f) && (tm[1] <= m_st[1] + 8.f);
            if (!__all(defer)) {
#pragma unroll
                for (int mi = 0; mi < 2; mi++) {
                    const float mn = fmaxf(m_st[mi], tm[mi]);
                    const float sf = __expf(m_st[mi] - mn);
                    m_st[mi] = mn;
                    l_st[mi] *= sf;
#pragma unroll
                    for (int dj = 0; dj < 4; dj++)
#pragma unroll
                        for (int r = 0; r < 4; r++) o[mi][dj][r] *= sf;
                }
            }
            // P = exp(S - m), row-sum, pack (already PV B-frag order)
            bf16x4 pk[2][4];
#pragma unroll
            for (int mi = 0; mi < 2; mi++) {
                float ts = 0.f;
#pragma unroll
                for (int nj = 0; nj < 4; nj++)
#pragma unroll
                    for (int r = 0; r < 4; r++) {
                        const float p = __expf(sc[mi][nj][r] - m_st[mi]);
                        ts += p;
                        pk[mi][nj][r] = (bf16)p;
                    }
                ts += __shfl_xor(ts, 16);
                ts += __shfl_xor(ts, 32);
                l_st[mi] += ts;
            }
            // O^T += V^T P^T
            __builtin_amdgcn_s_setprio(1);
#pragma unroll
            for (int kc = 0; kc < 2; kc++) {
                bf16x8 vf[4], pf2[2];
#pragma unroll
                for (int mi = 0; mi < 2; mi++) {
                    bf16x8 t;
#pragma unroll
                    for (int r = 0; r < 4; r++) { t[r] = pk[mi][2 * kc][r]; t[r + 4] = pk[mi][2 * kc + 1][r]; }
                    pf2[mi] = t;
                }
#pragma unroll
                for (int dj = 0; dj < 4; dj++)
                    vf[dj] = *(const bf16x8*)&Vts[cur][dj * 16 + lr][kc * 32 + lg * 8];
#pragma unroll
                for (int mi = 0; mi < 2; mi++)
#pragma unroll
                    for (int dj = 0; dj < 4; dj++)
                        o[mi][dj] = mfma16(vf[dj], pf2[mi], o[mi][dj]);
            }
            __builtin_amdgcn_s_setprio(0);
        }

        if (pf) WRITE(cur ^ 1);          // overwrite target's readers fenced at sb-1
        __syncthreads();                 // writes visible; single barrier per iter
        cur ^= 1;
    }

    // normalize + in-place store (O^T: lane owns q=lr col, d=lg*4+r rows)
#pragma unroll
    for (int mi = 0; mi < 2; mi++) {
        const float inv = 1.f / l_st[mi];
        const size_t rowoff = qbase + (size_t)(mi * 16 + lr) * NQ_;
#pragma unroll
        for (int dj = 0; dj < 4; dj++) {
            bf16x4 st;
#pragma unroll
            for (int r = 0; r < 4; r++) st[r] = (bf16)(o[mi][dj][r] * inv);
            *(bf16x4*)(QC + rowoff + dj * 16 + lg * 4) = st;
        }
    }
}

// ---------------------------------------------------------------------------
// LayerNorm, one 64-lane wave per 512-wide row, bf16x8 loads.
// ---------------------------------------------------------------------------
template <bool F32OUT>
__global__ __launch_bounds__(256) void ln_kernel(
    const bf16* __restrict__ xa, const bf16* __restrict__ xb,
    const float* __restrict__ w, const float* __restrict__ bias,
    void* __restrict__ outv)
{
    const int row = blockIdx.x * 4 + (threadIdx.x >> 6);
    const int ln = threadIdx.x & 63;
    const size_t base = (size_t)row * 512 + ln * 8;
    const bf16x8 va = *(const bf16x8*)(xa + base);
    const bf16x8 vb = *(const bf16x8*)(xb + base);
    float x[8];
    float s = 0.f;
#pragma unroll
    for (int i = 0; i < 8; i++) { x[i] = (float)va[i] + (float)vb[i]; s += x[i]; }
#pragma unroll
    for (int off = 32; off >= 1; off >>= 1) s += __shfl_xor(s, off);
    const float mean = s * (1.f / 512.f);
    float ss = 0.f;
#pragma unroll
    for (int i = 0; i < 8; i++) { x[i] -= mean; ss += x[i] * x[i]; }
#pragma unroll
    for (int off = 32; off >= 1; off >>= 1) ss += __shfl_xor(ss, off);
    const float inv = rsqrtf(ss * (1.f / 512.f) + 1e-5f);
    const f32x4 w0 = *(const f32x4*)(w + ln * 8);
    const f32x4 w1 = *(const f32x4*)(w + ln * 8 + 4);
    const f32x4 b0 = *(const f32x4*)(bias + ln * 8);
    const f32x4 b1 = *(const f32x4*)(bias + ln * 8 + 4);
    if constexpr (F32OUT) {
        f32x4 y0, y1;
#pragma unroll
        for (int i = 0; i < 4; i++) {
            y0[i] = x[i] * inv * w0[i] + b0[i];
            y1[i] = x[4 + i] * inv * w1[i] + b1[i];
        }
        *(f32x4*)((float*)outv + base) = y0;
        *(f32x4*)((float*)outv + base + 4) = y1;
    } else {
        bf16x8 y;
#pragma unroll
        for (int i = 0; i < 4; i++) {
            y[i] = (bf16)(x[i] * inv * w0[i] + b0[i]);
            y[4 + i] = (bf16)(x[4 + i] * inv * w1[i] + b1[i]);
        }
        *(bf16x8*)((bf16*)outv + base) = y;
    }
}

// ---------------------------------------------------------------------------
extern "C" void kernel_launch(void* const* d_in, const int* in_sizes, int n_in,
                              void* d_out, int out_size, void* d_ws, size_t ws_size,
                              hipStream_t stream)
{
    const float* inputs = (const float*)d_in[0];
    const float* Wq = (const float*)d_in[1];
    const float* bq = (const float*)d_in[2];
    const float* Wk = (const float*)d_in[3];
    const float* bk = (const float*)d_in[4];
    const float* Wv = (const float*)d_in[5];
    const float* bv = (const float*)d_in[6];
    const float* Wr = (const float*)d_in[7];
    const float* br = (const float*)d_in[8];
    const float* Wo = (const float*)d_in[9];
    const float* bo = (const float*)d_in[10];
    const float* ln1w = (const float*)d_in[11];
    const float* ln1b = (const float*)d_in[12];
    const float* Wfc = (const float*)d_in[13];
    const float* bfc = (const float*)d_in[14];
    const float* ln2w = (const float*)d_in[15];
    const float* ln2b = (const float*)d_in[16];
    float* out = (float*)d_out;

    // Workspace layout (~117 MB):
    const size_t MB = 1024ull * 1024ull;
    char* ws = (char*)d_ws;
    bf16* qc   = (bf16*)(ws);               // 32MB [M][1024] q -> attn out (in place)
    bf16* kb   = (bf16*)(ws + 32 * MB);     // 32MB [M][1024] k; post-attn: att|ln1
    bf16* vt   = (bf16*)(ws + 64 * MB);     // 32MB v^T; post-attn: fcb
    bf16* xin  = (bf16*)(ws + 96 * MB);     // 16MB bf16 inputs
    bf16* wall = (bf16*)(ws + 112 * MB);    // 3.5MB [3584][512] Wq|Wk|Wv|Wr
    bf16* wot  = (bf16*)(ws + 112 * MB + 3670016);            // 1MB [512][1024]
    bf16* wfct = (bf16*)(ws + 112 * MB + 3670016 + 1048576);  // 0.5MB [512][512]
    float* ball = (float*)(ws + 112 * MB + 3670016 + 1048576 + 524288);  // 14KB
    bf16* wrt  = wall + (size_t)3072 * 512;
    bf16* resb = (bf16*)d_out;              // residual in d_out's spare bytes
    bf16* att  = kb;                        // 16MB (kb dead after attention)
    bf16* ln1  = kb + (size_t)8 * MB;       // 16MB (second half of kb)
    bf16* fcb  = vt;                        // 16MB (vt dead after attention)

    const dim3 blk(256);

    // fused prep (conv | headw | plain | bias)
    prep_all_kernel<<<dim3(4750), blk, 0, stream>>>(
        inputs, Wq, Wk, Wv, Wr, Wo, Wfc, bq, bk, bv, br,
        xin, wall, wrt, wot, wfct, ball);

    // fused QKV + residual projection (N=3584)
    gemm_qkvr_kernel<<<dim3(28, 128), blk, 0, stream>>>(xin, wall, ball, qc, kb, vt, resb);
    // attention (in place over qc)
    mfma_attn_kernel<<<dim3(B_ * HN_ * 4), blk, 0, stream>>>(kb, vt, qc);
    // att = tanh(concat @ Wo + bo)
    gemm_std_kernel<2><<<dim3(4, 128), blk, 0, stream>>>(qc, wot, bo, att, 1024);
    // ln1 = LN1(att + resb)
    ln_kernel<false><<<dim3(4096), blk, 0, stream>>>(att, resb, ln1w, ln1b, ln1);
    // fcb = relu(ln1 @ Wfc + bfc)
    gemm_std_kernel<1><<<dim3(4, 128), blk, 0, stream>>>(ln1, wfct, bfc, fcb, 512);
    // out = LN2(fcb + ln1)  (f32 final)
    ln_kernel<true ><<<dim3(4096), blk, 0, stream>>>(fcb, ln1, ln2w, ln2b, out);
}